// Round 4
// baseline (354.358 us; speedup 1.0000x reference)
//
#include <hip/hip_runtime.h>
#include <hip/hip_bf16.h>

// Problem constants
#define BATCH   2048
#define IN_CH   12
#define UPLAG   2048
#define STEP    4
#define FEAT    512              // UPLAG/STEP
#define DIN     6144             // IN_CH*FEAT
#define HIDDEN  1024
#define OUTPUT  256

typedef __bf16 bf16x8 __attribute__((ext_vector_type(8)));
typedef float  f32x4  __attribute__((ext_vector_type(4)));

__device__ __forceinline__ unsigned short f2bf(float f) {
  unsigned int u = __builtin_bit_cast(unsigned int, f);
  unsigned int r = (u + 0x7fffu + ((u >> 16) & 1u)) >> 16;   // RNE
  return (unsigned short)r;
}

__device__ __forceinline__ float bf2f(unsigned short h) {
  unsigned int u = ((unsigned int)h) << 16;
  return __builtin_bit_cast(float, u);
}

__device__ __forceinline__ void async_copy16(const unsigned short* g, unsigned short* l) {
  __builtin_amdgcn_global_load_lds(
      (const __attribute__((address_space(1))) unsigned int*)g,
      (__attribute__((address_space(3))) unsigned int*)l, 16, 0, 0);
}

// ---------------------------------------------------------------------------
// Kernel 1 (fused prep): sectioned grid.
//   blocks [0, 4096)        : conv+cast, grid-stride (12 iters/thread)
//   blocks [4096, 5632)     : W2 transpose-cast, 64x64 tiles
//   blocks [5632, 5696)     : W3 transpose-cast, 64x64 tiles
// ---------------------------------------------------------------------------
#define CONV_BLOCKS 4096
#define W2T_BLOCKS  1536   // (1024/64) x (6144/64) = 16 x 96
#define W3T_BLOCKS  64     // (256/64)  x (1024/64) =  4 x 16

__global__ __launch_bounds__(256) void prep_kernel(
    const float* __restrict__ x, const float* __restrict__ W1,
    const float* __restrict__ b1, unsigned short* __restrict__ flatA,
    const float* __restrict__ W2, unsigned short* __restrict__ W2T,
    const float* __restrict__ W3, unsigned short* __restrict__ W3T)
{
  __shared__ float tile[64][65];
  const int t = threadIdx.x;
  int b = blockIdx.x;

  if (b < CONV_BLOCKS) {
    const int total = BATCH * DIN;
    for (int gid = b * 256 + t; gid < total; gid += CONV_BLOCKS * 256) {
      int cf = gid % DIN;          // c*FEAT + f
      int c  = cf >> 9;            // /512
      float4 xv = ((const float4*)x)[gid];
      float4 wv = ((const float4*)W1)[c];
      float v = xv.x * wv.x + xv.y * wv.y + xv.z * wv.z + xv.w * wv.w + b1[c];
      flatA[gid] = f2bf(v);
    }
    return;
  }

  const float* in; unsigned short* outp; int R, Ncol, bx, by;
  if (b < CONV_BLOCKS + W2T_BLOCKS) {
    int idx = b - CONV_BLOCKS;
    in = W2; outp = W2T; R = DIN; Ncol = HIDDEN;
    bx = (idx & 15) * 64; by = (idx >> 4) * 64;
  } else {
    int idx = b - CONV_BLOCKS - W2T_BLOCKS;
    in = W3; outp = W3T; R = HIDDEN; Ncol = OUTPUT;
    bx = (idx & 3) * 64; by = (idx >> 2) * 64;
  }
  int tx = t & 63, ty = t >> 6;     // 4 rows per pass
  #pragma unroll
  for (int i = 0; i < 64; i += 4)
    tile[ty + i][tx] = in[(size_t)(by + ty + i) * Ncol + bx + tx];
  __syncthreads();
  #pragma unroll
  for (int i = 0; i < 64; i += 4)
    outp[(size_t)(bx + ty + i) * R + by + tx] = f2bf(tile[tx][ty + i]);
}

// ---------------------------------------------------------------------------
// Kernel 2: GEMM1, split-K=6, XCD swizzle, BK=64, XOR-swizzled LDS layout.
// LDS k-chunk swizzle: LDS slot (row, kpos) holds global k-chunk
// kpos ^ (row&7); applied on the GLOBAL address of global_load_lds (LDS
// dests stay wave-uniform + lane*16). Fragment read de-swizzles -> b128
// reads land 2 lanes per 16B bank-unit (free), vs 8-way conflict before.
// ---------------------------------------------------------------------------
#define G1_BM 128
#define G1_BN 128
#define G1_BK 64
#define SPLITK 6

__global__ __launch_bounds__(256, 2) void gemm1_kernel(
    const unsigned short* __restrict__ A,   // [M,K]
    const unsigned short* __restrict__ BT,  // [N,K]
    unsigned short* __restrict__ Cp,        // [SPLITK, M, N] bf16
    int M, int N, int K)
{
  __shared__ unsigned short As[G1_BM * G1_BK];   // 16 KB
  __shared__ unsigned short Bs[G1_BN * G1_BK];   // 16 KB
  const int t    = threadIdx.x;
  const int lane = t & 63;
  const int wave = t >> 6;

  // swizzle decode: xcd group g owns M-tiles {2g, 2g+1}
  int b    = blockIdx.x;
  int xcdg = b & 7;
  int rest = b >> 3;          // 0..95
  int xt   = rest & 7;        // n-tile 0..7
  int zz   = rest >> 3;       // 0..11
  int zt   = zz >> 1;         // k-slice 0..5
  int yt   = (xcdg << 1) | (zz & 1);  // m-tile 0..15

  const int m0 = yt * G1_BM;
  const int n0 = xt * G1_BN;
  const int Ks = K / SPLITK;  // 1024
  const int kbeg = zt * Ks;

  const int wm = (wave >> 1) * 64;
  const int wn = (wave & 1) * 64;
  const int lm = lane & 15;
  const int kgrp = lane >> 4;          // 0..3

  f32x4 acc[4][4];
  #pragma unroll
  for (int i = 0; i < 4; i++)
    #pragma unroll
    for (int j = 0; j < 4; j++) {
      f32x4 z = {0.f, 0.f, 0.f, 0.f};
      acc[i][j] = z;
    }

  const unsigned short* Ag = A  + (size_t)m0 * K + kbeg;
  const unsigned short* Bg = BT + (size_t)n0 * K + kbeg;

  for (int kk = 0; kk < Ks; kk += G1_BK) {
    // stage A: 128 rows x 8 chunks(16B) = 1024 chunks = 4 rounds x 256 thr
    #pragma unroll
    for (int r = 0; r < 4; ++r) {
      int c = r * 256 + t;
      int row = c >> 3;
      int gk  = (c & 7) ^ (row & 7);
      async_copy16(Ag + (size_t)row * K + kk + gk * 8, As + c * 8);
    }
    #pragma unroll
    for (int r = 0; r < 4; ++r) {
      int c = r * 256 + t;
      int row = c >> 3;
      int gk  = (c & 7) ^ (row & 7);
      async_copy16(Bg + (size_t)row * K + kk + gk * 8, Bs + c * 8);
    }
    __syncthreads();

    #pragma unroll
    for (int s = 0; s < 2; ++s) {
      const int kch = kgrp + s * 4;
      bf16x8 af[4], bfr[4];
      #pragma unroll
      for (int i = 0; i < 4; i++) {
        int row = wm + i * 16 + lm;
        af[i] = *(const bf16x8*)(As + row * G1_BK + ((kch ^ (row & 7)) * 8));
      }
      #pragma unroll
      for (int j = 0; j < 4; j++) {
        int row = wn + j * 16 + lm;
        bfr[j] = *(const bf16x8*)(Bs + row * G1_BK + ((kch ^ (row & 7)) * 8));
      }
      #pragma unroll
      for (int i = 0; i < 4; i++)
        #pragma unroll
        for (int j = 0; j < 4; j++)
          acc[i][j] = __builtin_amdgcn_mfma_f32_16x16x32_bf16(af[i], bfr[j], acc[i][j], 0, 0, 0);
    }
    __syncthreads();
  }

  // epilogue: bf16 partials. C/D layout: col=lane&15, row=(lane>>4)*4+reg
  unsigned short* Co = Cp + (size_t)zt * M * N;
  const int rbase = kgrp * 4;
  #pragma unroll
  for (int i = 0; i < 4; i++)
    #pragma unroll
    for (int j = 0; j < 4; j++) {
      int col = n0 + wn + j * 16 + lm;
      #pragma unroll
      for (int r = 0; r < 4; r++) {
        int row = m0 + wm + i * 16 + rbase + r;
        Co[(size_t)row * N + col] = f2bf(acc[i][j][r]);
      }
    }
}

// ---------------------------------------------------------------------------
// Kernel 3: split-K reduce + bias + ReLU -> H bf16 [M, HIDDEN]
// ---------------------------------------------------------------------------
__global__ __launch_bounds__(256) void reduce_bias_relu(
    const unsigned short* __restrict__ Cp, const float* __restrict__ b2,
    unsigned short* __restrict__ H)
{
  const int MN = BATCH * HIDDEN;
  int i4 = blockIdx.x * 256 + threadIdx.x;        // x4 index
  if (i4 >= MN / 4) return;
  float4 s = {0.f, 0.f, 0.f, 0.f};
  #pragma unroll
  for (int p = 0; p < SPLITK; ++p) {
    ushort4 a = ((const ushort4*)(Cp + (size_t)p * MN))[i4];
    s.x += bf2f(a.x); s.y += bf2f(a.y); s.z += bf2f(a.z); s.w += bf2f(a.w);
  }
  int col = (i4 * 4) & (HIDDEN - 1);
  float4 bb = *(const float4*)(b2 + col);
  ushort4 o;
  o.x = f2bf(fmaxf(s.x + bb.x, 0.f));
  o.y = f2bf(fmaxf(s.y + bb.y, 0.f));
  o.z = f2bf(fmaxf(s.z + bb.z, 0.f));
  o.w = f2bf(fmaxf(s.w + bb.w, 0.f));
  ((ushort4*)H)[i4] = o;
}

// ---------------------------------------------------------------------------
// Kernel 4: GEMM2 split-K=4, BK=64, XOR-swizzled LDS, bf16 partials.
// ---------------------------------------------------------------------------
#define SPLITK2 4

__global__ __launch_bounds__(256, 2) void gemm2_kernel(
    const unsigned short* __restrict__ A,   // [M, K]
    const unsigned short* __restrict__ BT,  // [N, K]
    unsigned short* __restrict__ Cp)        // [SPLITK2, M, N] bf16
{
  const int M = BATCH, N = OUTPUT, K = HIDDEN;
  __shared__ unsigned short As[64 * 64];   // 8 KB
  __shared__ unsigned short Bs[64 * 64];   // 8 KB
  const int t    = threadIdx.x;
  const int lane = t & 63;
  const int wave = t >> 6;
  const int m0 = blockIdx.y * 64;
  const int n0 = blockIdx.x * 64;
  const int Ks = K / SPLITK2;              // 256
  const int kbeg = blockIdx.z * Ks;
  const int wm = (wave >> 1) * 32;
  const int wn = (wave & 1) * 32;
  const int lm = lane & 15;
  const int kgrp = lane >> 4;

  f32x4 acc[2][2];
  #pragma unroll
  for (int i = 0; i < 2; i++)
    #pragma unroll
    for (int j = 0; j < 2; j++) {
      f32x4 z = {0.f, 0.f, 0.f, 0.f};
      acc[i][j] = z;
    }

  const unsigned short* Ag = A  + (size_t)m0 * K + kbeg;
  const unsigned short* Bg = BT + (size_t)n0 * K + kbeg;

  for (int kk = 0; kk < Ks; kk += 64) {
    // 64 rows x 8 chunks = 512 chunks = 2 rounds x 256 thr
    #pragma unroll
    for (int r = 0; r < 2; ++r) {
      int c = r * 256 + t;
      int row = c >> 3;
      int gk  = (c & 7) ^ (row & 7);
      async_copy16(Ag + (size_t)row * K + kk + gk * 8, As + c * 8);
    }
    #pragma unroll
    for (int r = 0; r < 2; ++r) {
      int c = r * 256 + t;
      int row = c >> 3;
      int gk  = (c & 7) ^ (row & 7);
      async_copy16(Bg + (size_t)row * K + kk + gk * 8, Bs + c * 8);
    }
    __syncthreads();

    #pragma unroll
    for (int s = 0; s < 2; ++s) {
      const int kch = kgrp + s * 4;
      bf16x8 af[2], bfr[2];
      #pragma unroll
      for (int i = 0; i < 2; i++) {
        int row = wm + i * 16 + lm;
        af[i] = *(const bf16x8*)(As + row * 64 + ((kch ^ (row & 7)) * 8));
      }
      #pragma unroll
      for (int j = 0; j < 2; j++) {
        int row = wn + j * 16 + lm;
        bfr[j] = *(const bf16x8*)(Bs + row * 64 + ((kch ^ (row & 7)) * 8));
      }
      #pragma unroll
      for (int i = 0; i < 2; i++)
        #pragma unroll
        for (int j = 0; j < 2; j++)
          acc[i][j] = __builtin_amdgcn_mfma_f32_16x16x32_bf16(af[i], bfr[j], acc[i][j], 0, 0, 0);
    }
    __syncthreads();
  }

  unsigned short* Co = Cp + (size_t)blockIdx.z * M * N;
  const int rbase = kgrp * 4;
  #pragma unroll
  for (int i = 0; i < 2; i++)
    #pragma unroll
    for (int j = 0; j < 2; j++) {
      int col = n0 + wn + j * 16 + lm;
      #pragma unroll
      for (int r = 0; r < 4; r++) {
        int row_o = m0 + wm + i * 16 + rbase + r;
        Co[(size_t)row_o * N + col] = f2bf(acc[i][j][r]);
      }
    }
}

// ---------------------------------------------------------------------------
// Kernel 5: GEMM2 split-K reduce + bias -> out fp32 [M, OUTPUT]
// ---------------------------------------------------------------------------
__global__ __launch_bounds__(256) void reduce2_bias(
    const unsigned short* __restrict__ Cp, const float* __restrict__ b3,
    float* __restrict__ out)
{
  const int MN = BATCH * OUTPUT;
  int i4 = blockIdx.x * 256 + threadIdx.x;
  if (i4 >= MN / 4) return;
  float4 s = {0.f, 0.f, 0.f, 0.f};
  #pragma unroll
  for (int p = 0; p < SPLITK2; ++p) {
    ushort4 a = ((const ushort4*)(Cp + (size_t)p * MN))[i4];
    s.x += bf2f(a.x); s.y += bf2f(a.y); s.z += bf2f(a.z); s.w += bf2f(a.w);
  }
  int col = (i4 * 4) & (OUTPUT - 1);
  float4 bb = *(const float4*)(b3 + col);
  float4 o = {s.x + bb.x, s.y + bb.y, s.z + bb.z, s.w + bb.w};
  ((float4*)out)[i4] = o;
}

// ---------------------------------------------------------------------------
extern "C" void kernel_launch(void* const* d_in, const int* in_sizes, int n_in,
                              void* d_out, int out_size, void* d_ws, size_t ws_size,
                              hipStream_t stream)
{
  const float* x  = (const float*)d_in[0];
  const float* W1 = (const float*)d_in[1];
  const float* b1 = (const float*)d_in[2];
  const float* W2 = (const float*)d_in[3];
  const float* b2 = (const float*)d_in[4];
  const float* W3 = (const float*)d_in[5];
  const float* b3 = (const float*)d_in[6];
  float* out = (float*)d_out;

  char* ws = (char*)d_ws;
  unsigned short* flatA = (unsigned short*)ws; ws += (size_t)BATCH * DIN * 2;
  unsigned short* W2T   = (unsigned short*)ws; ws += (size_t)HIDDEN * DIN * 2;
  unsigned short* W3T   = (unsigned short*)ws; ws += (size_t)OUTPUT * HIDDEN * 2;
  unsigned short* Cpart = (unsigned short*)ws; ws += (size_t)SPLITK * BATCH * HIDDEN * 2;
  unsigned short* H     = (unsigned short*)ws; ws += (size_t)BATCH * HIDDEN * 2;
  unsigned short* Cp2   = (unsigned short*)ws; ws += (size_t)SPLITK2 * BATCH * OUTPUT * 2;

  // 1. fused prep: conv (grid-stride) + W2/W3 transpose-casts
  prep_kernel<<<CONV_BLOCKS + W2T_BLOCKS + W3T_BLOCKS, 256, 0, stream>>>(
      x, W1, b1, flatA, W2, W2T, W3, W3T);
  // 2. GEMM1 split-K=6, XCD swizzle, BK=64: 768 blocks
  gemm1_kernel<<<768, 256, 0, stream>>>(flatA, W2T, Cpart, BATCH, HIDDEN, DIN);
  // 3. reduce + bias + relu
  reduce_bias_relu<<<(BATCH * HIDDEN / 4) / 256, 256, 0, stream>>>(Cpart, b2, H);
  // 4. GEMM2 split-K=4, BK=64: 512 blocks
  gemm2_kernel<<<dim3(OUTPUT / 64, BATCH / 64, SPLITK2), 256, 0, stream>>>(H, W3T, Cp2);
  // 5. reduce + bias
  reduce2_bias<<<(BATCH * OUTPUT / 4) / 256, 256, 0, stream>>>(Cp2, b3, out);
}